// Round 4
// baseline (11.984 us; speedup 1.0000x reference)
//
#include <hip/hip_runtime.h>
#include <hip/hip_bf16.h>

// Hierarchical softmax loss:
//   loss = (1/B) * sum_b sum_{l=0..L-1} softplus(-scores[b, 2^l - 1 + bit_l])
// where bit_l = (class_indices[b] >> (L-1-l)) & 1, L = ceil(log2(V)).
//
// Single gather kernel (64 blocks). out[0] is zeroed by a 4-byte memset node;
// each block contributes one device-scope float atomicAdd. Both candidate
// columns (2^l-1, 2^l) are loaded concurrently with the index load so the
// critical path is ONE cold-HBM round trip, not two dependent ones.

__global__ __launch_bounds__(256) void hsm_gather_kernel(
    const float* __restrict__ scores,
    const int* __restrict__ cls,
    float* __restrict__ out,
    int B, int V, int code_len, float invB) {

    const int tid = threadIdx.x;
    const int lvl0 = tid & 15;          // level lane within a row's 16 threads
    const int rowInBlk = tid >> 4;      // 16 rows per 256-thread block
    const int rowsPerBlk = blockDim.x >> 4;

    float acc = 0.0f;
    for (int r = blockIdx.x * rowsPerBlk + rowInBlk; r < B;
         r += gridDim.x * rowsPerBlk) {
        const float* row = scores + (size_t)r * (size_t)V;
        const int ci = cls[r];          // issues concurrently with a,b below
        for (int l = lvl0; l < code_len; l += 16) {   // single iter at L=16
            const float a = row[(1 << l) - 1];  // left candidate (bit==0)
            const float b = row[(1 << l)];      // right candidate (bit==1)
            const int bit = (ci >> (code_len - 1 - l)) & 1;
            const float x = bit ? b : a;
            // softplus(-x) = -log(sigmoid(x)), numerically stable
            acc += log1pf(__expf(-fabsf(x))) + fmaxf(-x, 0.0f);
        }
    }

    // wave reduction (64 lanes)
    #pragma unroll
    for (int off = 32; off > 0; off >>= 1)
        acc += __shfl_down(acc, off, 64);

    __shared__ float wsum[4];
    const int lane = tid & 63;
    const int wid = tid >> 6;
    if (lane == 0) wsum[wid] = acc;
    __syncthreads();

    if (tid == 0) {
        const float blocksum = wsum[0] + wsum[1] + wsum[2] + wsum[3];
        atomicAdd(out, blocksum * invB);   // device-scope on global by default
    }
}

extern "C" void kernel_launch(void* const* d_in, const int* in_sizes, int n_in,
                              void* d_out, int out_size, void* d_ws, size_t ws_size,
                              hipStream_t stream) {
    const float* scores = (const float*)d_in[0];
    const int* class_indices = (const int*)d_in[1];
    float* out = (float*)d_out;

    const int B = in_sizes[1];                               // class_indices: [B]
    const int V = (int)(in_sizes[0] / (size_t)in_sizes[1]);  // scores: [B, V]

    int code_len = 0;
    while ((1LL << code_len) < (long long)V) ++code_len;

    // zero the scalar output each launch (graph-capturable async memset node)
    hipMemsetAsync(out, 0, (size_t)out_size * sizeof(float), stream);

    const int rowsPerBlk = 16;
    const int grid = (B + rowsPerBlk - 1) / rowsPerBlk;      // 64 for B=1024
    hsm_gather_kernel<<<grid, 256, 0, stream>>>(scores, class_indices, out,
                                                B, V, code_len, 1.0f / (float)B);
}